// Round 22
// baseline (1107.625 us; speedup 1.0000x reference)
//
#include <hip/hip_runtime.h>
#include <hip/hip_bf16.h>
#include <stdint.h>

#define E_ 4
#define T_ 4096
#define D_ 2048
#define H_ 8192

typedef __attribute__((ext_vector_type(8))) short bf16x8;
typedef __attribute__((ext_vector_type(4))) float f32x4;
typedef __attribute__((ext_vector_type(4))) unsigned short u16x4;

__device__ __forceinline__ unsigned short f2bf(float f) {
    unsigned int u = __float_as_uint(f);
    u = u + 0x7fffu + ((u >> 16) & 1u);
    return (unsigned short)(u >> 16);
}

// async global->LDS, 16B per lane. LDS dest is wave-uniform base; HW adds lane*16.
// (r19/r20 lesson: offset-immediate path corrupts data — always offset==0.)
__device__ __forceinline__ void async16(const unsigned short* g, unsigned short* l) {
    auto gp = (const __attribute__((address_space(1))) unsigned int*)g;
    auto lp = (__attribute__((address_space(3))) unsigned int*)l;
    __builtin_amdgcn_global_load_lds(gp, lp, 16, 0, 0);
}

__device__ __forceinline__ f32x4 mfma16(bf16x8 a, bf16x8 b, f32x4 c) {
    return __builtin_amdgcn_mfma_f32_16x16x32_bf16(a, b, c, 0, 0, 0);
}

// ---------------- x: f32 -> bf16 ----------------
__global__ void cvt_x_kernel(const float4* __restrict__ in, uint2* __restrict__ out, long n4) {
    long i = (long)blockIdx.x * blockDim.x + threadIdx.x;
    long stride = (long)gridDim.x * blockDim.x;
    for (; i < n4; i += stride) {
        float4 v = in[i];
        uint2 o;
        o.x = (unsigned)f2bf(v.x) | ((unsigned)f2bf(v.y) << 16);
        o.y = (unsigned)f2bf(v.z) | ((unsigned)f2bf(v.w) << 16);
        out[i] = o;
    }
}

// ---------------- W (R x C, f32) -> Wt (C x R, bf16) per expert ----------------
__global__ void transpose_cvt_kernel(const float* __restrict__ W, unsigned short* __restrict__ Wt,
                                     int R, int C) {
    __shared__ float tile[64][65];
    const float* Wp = W + (size_t)blockIdx.z * R * C;
    unsigned short* Wtp = Wt + (size_t)blockIdx.z * R * C;
    const int c0 = blockIdx.x * 64, r0 = blockIdx.y * 64;
    const int tc = threadIdx.x & 63;
    const int tr = threadIdx.x >> 6;
#pragma unroll
    for (int i = 0; i < 16; ++i) {
        int r = tr * 16 + i;
        tile[r][tc] = Wp[(size_t)(r0 + r) * C + c0 + tc];
    }
    __syncthreads();
#pragma unroll
    for (int i = 0; i < 16; ++i) {
        int r = tr * 16 + i;
        Wtp[(size_t)(c0 + r) * R + r0 + tc] = f2bf(tile[tc][r]);
    }
}

// -------- 256x256 GEMM: 2-phase/K-tile, 32-MFMA clusters, cadence+certified reads --------
// r22: merge r17's 4 phases/K-tile into 2 (barriers 4->2/K-tile; r14->r16 showed barrier
// reduction is the lever that moved twice). Kept: region-cadence staging, counted vmcnt,
// one-barrier-ahead certified reads, verified swizzle/supertile/epilogue.
// Per K-tile t (slot S), a[] alternates lo/hi:
//  PH_A: stage a-hi(t+1)->S^1 [2]; cluster acc[0..3][*] (a-lo x b, 32 MFMA);
//        post: RD a-hi(t)->a [8]; bar
//  PH_B: stage a-lo/B(t+2)->S [6]; vmcnt(6) certifies tile t+1; cluster acc[4..7][*]
//        (a-hi x b, 32 MFMA); post: RD b(t+1)+a-lo(t+1) [16]; bar
// VMEM ledger (steady, per wave): enter A=6 {a-lo,B}(t+1); A:+2=8; B:+6=14; vmcnt(6)
//   completes oldest 8 = tile t+1 exactly. Prologue: tile0 full(8)+tile1 a-lo/B(6);
//   vmcnt(6) -> tile0 landed, 6 left = invariant. Tail: stages/reads guarded; vmcnt(0).
// Region-death: a-lo/B(t) dead after PH_A(t) bar (in-order DS + cluster dep);
//   a-hi(t) dead after PH_B(t) bar -> all stage targets one-barrier-dead.
template <int K, int OUT_MODE>
__global__ __launch_bounds__(512, 2) void gemm256_kernel(
    const unsigned short* __restrict__ A,   // [E][M][K]
    const unsigned short* __restrict__ Bt,  // [E][N][K]
    const float* __restrict__ bias,         // [E][N]
    void* __restrict__ Cout,                // [E][M][N]
    int M, int N)
{
    constexpr int BK = 64;
    constexpr int NT = K / BK;              // even (32 / 128)
    __shared__ __align__(16) unsigned short L[2][2][2][128][64];

    // ---- XCD chunk + L3 supertile remap (r5-validated) ----
    const int nx = gridDim.x, ny = gridDim.y;
    const int nwg = nx * ny * gridDim.z;
    const int w = (blockIdx.z * ny + blockIdx.y) * nx + blockIdx.x;
    const int cpx = nwg >> 3;
    const int xcd = w & 7;
    const int c = w >> 3;
    const int CR = cpx / nx;
    const int GX = (nx % 16 == 0) ? 16 : nx;
    const int g = c / (GX * CR);
    const int r1 = c - g * (GX * CR);
    const int byl = r1 / GX;
    const int bxi = r1 - byl * GX;
    const int fy = xcd * CR + byl;
    const int bx = g * GX + bxi;
    const int e = fy / ny;
    const int by = fy - e * ny;

    const unsigned short* Ae = A + (size_t)e * M * K;
    const unsigned short* Be = Bt + (size_t)e * N * K;
    const int bm0 = by * 256;
    const int bn0 = bx * 256;

    const int tid = threadIdx.x;
    const int lane = tid & 63;
    const int wid = tid >> 6;
    const int wr = wid >> 2;
    const int wc = wid & 3;

    // ---- staging geometry: one async16 call = one 64-row region slice (8 rows/wave)
    const int srow8 = wid * 8 + (lane >> 3);
    const int skel = 8 * ((lane & 7) ^ (lane >> 3));
    const unsigned short* Abase = Ae + (size_t)(bm0 + srow8) * K + skel;
    const unsigned short* Bbase = Be + (size_t)(bn0 + srow8) * K + skel;

#define STG_A(S_, T_, H_, RO_) \
    async16(Abase + ((size_t)((H_) * 128 + (RO_)) * K + (T_) * BK), \
            &L[S_][0][H_][(RO_) + wid * 8][0])
#define STG_B(S_, T_, H_, RO_) \
    async16(Bbase + ((size_t)((H_) * 128 + (RO_)) * K + (T_) * BK), \
            &L[S_][1][H_][(RO_) + wid * 8][0])

    // ---- fragment-read geometry (r5-verified swizzle) ----
    const int fr = lane & 15;
    const int kq = lane >> 4;
    const int ksw = (lane & 7) << 3;
    const int bh = wc >> 1;
    const int brb = (wc & 1) * 64;

#define RD_A(S_, MOFF_) \
    _Pragma("unroll") for (int m = 0; m < 4; ++m) \
    _Pragma("unroll") for (int kk = 0; kk < 2; ++kk) \
        a[m][kk] = *(const bf16x8*)&L[S_][0][wr][(m + (MOFF_)) * 16 + fr][(kk * 32 + kq * 8) ^ ksw]
#define RD_B(S_) \
    _Pragma("unroll") for (int n = 0; n < 4; ++n) \
    _Pragma("unroll") for (int kk = 0; kk < 2; ++kk) \
        b[n][kk] = *(const bf16x8*)&L[S_][1][bh][brb + n * 16 + fr][(kk * 32 + kq * 8) ^ ksw]

#define CLOSEBAR do { __builtin_amdgcn_s_barrier(); __builtin_amdgcn_sched_barrier(0); } while (0)
#define MFMA_H(MB_) do { __builtin_amdgcn_s_setprio(1); \
    _Pragma("unroll") for (int m = 0; m < 4; ++m) \
    _Pragma("unroll") for (int n = 0; n < 4; ++n) \
    _Pragma("unroll") for (int kk = 0; kk < 2; ++kk) \
        acc[(MB_) + m][n] = mfma16(a[m][kk], b[n][kk], acc[(MB_) + m][n]); \
    __builtin_amdgcn_s_setprio(0); } while (0)

    f32x4 acc[8][4] = {};
    bf16x8 a[4][2], b[4][2];

    // ---- prologue: tile0 full (8 calls) + tile1 a-lo/B (6 calls)
    STG_A(0, 0, 0, 0);  STG_A(0, 0, 1, 0);   // a-lo(0)
    STG_B(0, 0, 0, 0);  STG_B(0, 0, 0, 64);  // B(0) h0
    STG_B(0, 0, 1, 0);  STG_B(0, 0, 1, 64);  // B(0) h1
    STG_A(0, 0, 0, 64); STG_A(0, 0, 1, 64);  // a-hi(0)
    STG_A(1, 1, 0, 0);  STG_A(1, 1, 1, 0);   // a-lo(1)
    STG_B(1, 1, 0, 0);  STG_B(1, 1, 0, 64);  // B(1) h0
    STG_B(1, 1, 1, 0);  STG_B(1, 1, 1, 64);  // B(1) h1
    asm volatile("s_waitcnt vmcnt(6)" ::: "memory"); // tile0 (oldest 8) landed
    __builtin_amdgcn_sched_barrier(0);
    __builtin_amdgcn_s_barrier();
    RD_B(0);                                  // preload b(tile0)
    RD_A(0, 0);                               // preload a-lo(tile0)

    // PH_A(T_, S_): stage a-hi(T_+1) into S_^1; cluster rows 0-3; read a-hi(T_) into a.
#define PH_A(T_, S_, HAS_NEXT_) do { \
        if (HAS_NEXT_) { STG_A((S_) ^ 1, (T_) + 1, 0, 64); STG_A((S_) ^ 1, (T_) + 1, 1, 64); } \
        __builtin_amdgcn_sched_barrier(0); \
        MFMA_H(0); \
        RD_A(S_, 4); \
        CLOSEBAR; \
    } while (0)

    // PH_B(T_, S_): stage a-lo/B(T_+2) into S_; vmcnt certifies T_+1; cluster rows 4-7;
    // read b+a-lo(T_+1) from S_^1.
#define PH_B(T_, S_, HAS_NEXT_, HAS_NEXT2_) do { \
        if (HAS_NEXT2_) { \
            STG_A(S_, (T_) + 2, 0, 0);  STG_A(S_, (T_) + 2, 1, 0); \
            STG_B(S_, (T_) + 2, 0, 0);  STG_B(S_, (T_) + 2, 0, 64); \
            STG_B(S_, (T_) + 2, 1, 0);  STG_B(S_, (T_) + 2, 1, 64); \
        } \
        if (HAS_NEXT2_) { asm volatile("s_waitcnt vmcnt(6)" ::: "memory"); } \
        else            { asm volatile("s_waitcnt vmcnt(0)" ::: "memory"); } \
        __builtin_amdgcn_sched_barrier(0); \
        MFMA_H(4); \
        if (HAS_NEXT_) { RD_B((S_) ^ 1); RD_A((S_) ^ 1, 0); } \
        CLOSEBAR; \
    } while (0)

    for (int j = 0; j < NT / 2 - 1; ++j) {
        const int tA = 2 * j, tB = tA + 1;
        PH_A(tA, 0, true);
        PH_B(tA, 0, true, (tA + 2 < NT));
        PH_A(tB, 1, (tB + 1 < NT));
        PH_B(tB, 1, (tB + 1 < NT), (tB + 2 < NT));
    }
    {
        const int tA = NT - 2, tB = NT - 1;
        PH_A(tA, 0, true);
        PH_B(tA, 0, true, false);   // vmcnt(0) certifies tile tB (last)
        PH_A(tB, 1, false);
        PH_B(tB, 1, false, false);
    }

#undef PH_A
#undef PH_B
#undef MFMA_H
#undef CLOSEBAR
#undef RD_A
#undef RD_B
#undef STG_A
#undef STG_B

    // ---- epilogue: LDS-transpose to contiguous row stores (r5-validated) ----
    constexpr int ST = 260;
    float* S = (float*)&L[0][0][0][0][0];
    const int rowq = (lane >> 4) * 4;
    const float* bp = bias + (size_t)e * N;
    const float4 bb4 = *(const float4*)(bp + bn0 + lane * 4);

    unsigned short* Y = (unsigned short*)Cout + (size_t)e * M * N;
    float* O = (float*)Cout + (size_t)e * M * N;

#pragma unroll
    for (int sg = 0; sg < 8; ++sg) {
        __syncthreads();
        if (wr == (sg >> 2)) {
            const int sl = sg & 3;
#pragma unroll
            for (int mm = 0; mm < 2; ++mm) {
#pragma unroll
                for (int n = 0; n < 4; ++n) {
#pragma unroll
                    for (int j2 = 0; j2 < 4; ++j2) {
                        S[(mm * 16 + rowq + j2) * ST + wc * 64 + n * 16 + fr] =
                            acc[2 * sl + mm][n][j2];
                    }
                }
            }
        }
        __syncthreads();
#pragma unroll
        for (int rr = 0; rr < 4; ++rr) {
            const int rl = wid * 4 + rr;
            const int rg = bm0 + sg * 32 + rl;
            f32x4 v = *(const f32x4*)&S[rl * ST + lane * 4];
            v[0] += bb4.x; v[1] += bb4.y; v[2] += bb4.z; v[3] += bb4.w;
            if (OUT_MODE == 0) {
                u16x4 o;
                o[0] = f2bf(fmaxf(v[0], 0.0f));
                o[1] = f2bf(fmaxf(v[1], 0.0f));
                o[2] = f2bf(fmaxf(v[2], 0.0f));
                o[3] = f2bf(fmaxf(v[3], 0.0f));
                *(u16x4*)(Y + (size_t)rg * N + bn0 + lane * 4) = o;
            } else {
                *(f32x4*)(O + (size_t)rg * N + bn0 + lane * 4) = v;
            }
        }
    }
}

extern "C" void kernel_launch(void* const* d_in, const int* in_sizes, int n_in,
                              void* d_out, int out_size, void* d_ws, size_t ws_size,
                              hipStream_t stream) {
    const float* x     = (const float*)d_in[0]; // (E,T,D)
    const float* fc1_w = (const float*)d_in[1]; // (E,D,H)
    const float* fc1_b = (const float*)d_in[2]; // (E,1,H)
    const float* fc2_w = (const float*)d_in[3]; // (E,H,D)
    const float* fc2_b = (const float*)d_in[4]; // (E,1,D)
    float* out = (float*)d_out;

    const size_t n_x  = (size_t)E_ * T_ * D_;
    const size_t n_w1 = (size_t)E_ * D_ * H_;
    const size_t n_w2 = (size_t)E_ * H_ * D_;
    const size_t n_y1 = (size_t)E_ * T_ * H_;

    const size_t need = (n_x + n_w1 + n_w2 + n_y1) * sizeof(unsigned short);
    if (ws_size < need) return;

    unsigned short* xb  = (unsigned short*)d_ws;
    unsigned short* w1t = xb + n_x;    // (E,H,D)
    unsigned short* w2t = w1t + n_w1;  // (E,D,H)
    unsigned short* y1  = w2t + n_w2;  // (E,T,H)

    cvt_x_kernel<<<2048, 256, 0, stream>>>((const float4*)x, (uint2*)xb, (long)(n_x / 4));
    {
        dim3 g(H_ / 64, D_ / 64, E_);
        transpose_cvt_kernel<<<g, 256, 0, stream>>>(fc1_w, w1t, D_, H_);
    }
    {
        dim3 g(D_ / 64, H_ / 64, E_);
        transpose_cvt_kernel<<<g, 256, 0, stream>>>(fc2_w, w2t, H_, D_);
    }
    // GEMM1: y1 = relu(x @ W1 + b1), bf16 out. M=T, N=H, K=D
    {
        dim3 g(H_ / 256, T_ / 256, E_);
        gemm256_kernel<D_, 0><<<g, 512, 0, stream>>>(xb, w1t, fc1_b, (void*)y1, T_, H_);
    }
    // GEMM2: out = y1 @ W2 + b2, f32 out. M=T, N=D, K=H
    {
        dim3 g(D_ / 256, T_ / 256, E_);
        gemm256_kernel<H_, 1><<<g, 512, 0, stream>>>(y1, w2t, fc2_b, (void*)out, T_, D_);
    }
}